// Round 1
// baseline (607.377 us; speedup 1.0000x reference)
//
#include <hip/hip_runtime.h>
#include <hip/hip_fp16.h>

typedef _Float16 half8 __attribute__((ext_vector_type(8)));
typedef _Float16 half2v __attribute__((ext_vector_type(2)));
typedef float float4v __attribute__((ext_vector_type(4)));
typedef float float2v __attribute__((ext_vector_type(2)));

#define BLOCK 256
#define ROWS_PER_BLOCK 64
// LDS row pitch in halfs: 96 data + 8 pad -> 208 B rows, keeps b128 frag reads
// 16B-aligned and reduces bank aliasing to 2-way (free per m136).
#define ROWPITCH 104

__global__ __launch_bounds__(BLOCK) void face_conv_kernel(
    const float* __restrict__ x,
    const float* __restrict__ w0,
    const float* __restrict__ w1,
    const float* __restrict__ w2,
    const float* __restrict__ bias,
    const int* __restrict__ fn,
    float* __restrict__ out,
    int N)
{
    // Per-wave private A tiles: 4 waves x 16 rows x 104 halfs = 13312 B
    __shared__ _Float16 A[4][16 * ROWPITCH];

    const int tid  = threadIdx.x;
    const int wave = tid >> 6;
    const int lane = tid & 63;
    const int m16  = lane & 15;   // 0..15
    const int quad = lane >> 4;   // 0..3

    // ---- Build B fragments (weights) in registers, once per wave ----
    // mfma_f32_16x16x32_f16 B-operand layout: B[k][n], n = lane&15, k = quad*8 + j.
    // Our GEMM: out[n][o] = sum_k A[n][k] * B[k][o], k = s*32 + c,
    // B[s*32+c][o] = w_s[o][c].  o-tile t covers o = t*16 + n.
    half8 bfrag[3][2];
    const float* wptr[3] = {w0, w1, w2};
    #pragma unroll
    for (int s = 0; s < 3; ++s) {
        #pragma unroll
        for (int t = 0; t < 2; ++t) {
            const int o = t * 16 + m16;
            const float* wr = wptr[s] + o * 32 + quad * 8;
            half8 f;
            #pragma unroll
            for (int j = 0; j < 8; ++j) f[j] = (_Float16)wr[j];
            bfrag[s][t] = f;
        }
    }
    const float bias0 = bias[m16];
    const float bias1 = bias[16 + m16];

    const int base = blockIdx.x * ROWS_PER_BLOCK + wave * 16;
    _Float16* Aw = A[wave];

    // ---- Phase A: gather + combine + f32->f16 convert; 4 rows per step ----
    // Lane (quad, m16): row = base + it*4 + quad, channels 2*m16, 2*m16+1.
    #pragma unroll
    for (int it = 0; it < 4; ++it) {
        const int rloc = it * 4 + quad;     // local row 0..15
        const int r = base + rloc;
        float2v g0 = {0.f, 0.f}, g1 = {0.f, 0.f}, g2 = {0.f, 0.f};
        if (r < N) {
            const int* fr = fn + (long)r * 9;
            int idx[9];
            #pragma unroll
            for (int j = 0; j < 9; ++j) idx[j] = fr[j];
            float2v v[9];
            #pragma unroll
            for (int j = 0; j < 9; ++j) {
                const int id = idx[j];
                if ((unsigned)id < (unsigned)N) {
                    v[j] = *(const float2v*)(x + (long)id * 32 + m16 * 2);
                } else {
                    v[j] = (float2v){0.f, 0.f};
                }
            }
            g0 = v[0];
            g1 = v[1] + v[3] + v[5] + v[7];
            g2 = v[2] + v[4] + v[6] + v[8];
        }
        // A-fragment layout target: A[m][k] halfs, row-major with ROWPITCH.
        _Float16* dst = Aw + rloc * ROWPITCH + m16 * 2;
        *(half2v*)(dst)      = (half2v){(_Float16)g0.x, (_Float16)g0.y};
        *(half2v*)(dst + 32) = (half2v){(_Float16)g1.x, (_Float16)g1.y};
        *(half2v*)(dst + 64) = (half2v){(_Float16)g2.x, (_Float16)g2.y};
    }

    __syncthreads();   // cross-lane LDS RAW within wave + keep block in step

    // ---- Phase B: 6 MFMAs per wave (16 rows x 32 outs, K=96) ----
    // A-operand layout: A[m = lane&15][k = quad*8 + j]  -> contiguous b128.
    float4v acc0 = {0.f, 0.f, 0.f, 0.f}, acc1 = {0.f, 0.f, 0.f, 0.f};
    #pragma unroll
    for (int s = 0; s < 3; ++s) {
        half8 a = *(half8*)(Aw + m16 * ROWPITCH + s * 32 + quad * 8);
        acc0 = __builtin_amdgcn_mfma_f32_16x16x32_f16(a, bfrag[s][0], acc0, 0, 0, 0);
        acc1 = __builtin_amdgcn_mfma_f32_16x16x32_f16(a, bfrag[s][1], acc1, 0, 0, 0);
    }

    // Epilogue: C/D layout col = lane&15, row = quad*4 + i.
    #pragma unroll
    for (int i = 0; i < 4; ++i) {
        const int r = base + quad * 4 + i;
        if (r < N) {
            out[(long)r * 32 + m16]      = acc0[i] + bias0;
            out[(long)r * 32 + 16 + m16] = acc1[i] + bias1;
        }
    }
}

extern "C" void kernel_launch(void* const* d_in, const int* in_sizes, int n_in,
                              void* d_out, int out_size, void* d_ws, size_t ws_size,
                              hipStream_t stream) {
    const float* x    = (const float*)d_in[0];
    const float* w0   = (const float*)d_in[1];
    const float* w1   = (const float*)d_in[2];
    const float* w2   = (const float*)d_in[3];
    const float* bias = (const float*)d_in[4];
    const int*   fn   = (const int*)d_in[5];
    // d_in[6] = face_is_pad (pattern: i >= N), d_in[7] = pad_size — both implied
    // by idx < N check, not needed at runtime.
    float* out = (float*)d_out;

    const int N = in_sizes[0] / 32;
    const int blocks = (N + ROWS_PER_BLOCK - 1) / ROWS_PER_BLOCK;
    face_conv_kernel<<<blocks, BLOCK, 0, stream>>>(x, w0, w1, w2, bias, fn, out, N);
}

// Round 2
// 377.287 us; speedup vs baseline: 1.6099x; 1.6099x over previous
//
#include <hip/hip_runtime.h>
#include <hip/hip_fp16.h>

typedef _Float16 half8 __attribute__((ext_vector_type(8)));
typedef _Float16 half4v __attribute__((ext_vector_type(4)));
typedef float float4v __attribute__((ext_vector_type(4)));

#define BLOCK 256
#define ROWS_PER_BLOCK 64
// LDS row pitch in halfs: 96 data + 8 pad -> 208 B rows (16B-aligned for b128).
#define ROWPITCH 104

// Pre-converted f16 weight fragments, laid out so each lane's bfrag[s][t] is a
// contiguous 16B: wh[(s*2+t)*512 + lane*8 + j] = w_s[(t*16+(lane&15))*32 + (lane>>4)*8 + j]
__device__ _Float16 g_wh[6 * 512];

__global__ void prep_weights(const float* __restrict__ w0,
                             const float* __restrict__ w1,
                             const float* __restrict__ w2) {
    const int t = threadIdx.x;           // 0..383
    const int st = t >> 6;               // s*2+tt, 0..5
    const int lane = t & 63;
    const int s = st >> 1, tt = st & 1;
    const float* w = (s == 0) ? w0 : (s == 1) ? w1 : w2;
    const int o = tt * 16 + (lane & 15);
    const int k = (lane >> 4) * 8;
    #pragma unroll
    for (int j = 0; j < 8; ++j)
        g_wh[st * 512 + lane * 8 + j] = (_Float16)w[o * 32 + k + j];
}

__global__ __launch_bounds__(BLOCK) void face_conv_kernel(
    const float* __restrict__ x,
    const float* __restrict__ bias,
    const int* __restrict__ fn,
    float* __restrict__ out,
    int N)
{
    // Per-wave private A tiles: 4 waves x 16 rows x 104 halfs = 13312 B
    __shared__ _Float16 A[4][16 * ROWPITCH];

    const int tid  = threadIdx.x;
    const int wave = tid >> 6;
    const int lane = tid & 63;
    const int m16  = lane & 15;   // 0..15
    const int quad = lane >> 4;   // 0..3
    const int oct  = lane >> 3;   // 0..7  (gather phase: row within half-tile)
    const int m8   = lane & 7;    // 0..7  (gather phase: channel quad)

    // ---- B fragments: direct 16B loads of pre-converted halves ----
    half8 bfrag[3][2];
    #pragma unroll
    for (int s = 0; s < 3; ++s)
        #pragma unroll
        for (int t = 0; t < 2; ++t)
            bfrag[s][t] = *(const half8*)(g_wh + (s * 2 + t) * 512 + lane * 8);
    const float bias0 = bias[m16];
    const float bias1 = bias[16 + m16];

    const int base = blockIdx.x * ROWS_PER_BLOCK + wave * 16;
    _Float16* Aw = A[wave];

    // ---- Phase A: gather + combine + convert; 8 rows per iteration, x4 loads ----
    // Lane (oct, m8): row rloc = it*8 + oct, channels m8*4 .. m8*4+3.
    // Hoist ALL index loads first so gathers of both iterations pipeline.
    int idx[2][9];
    #pragma unroll
    for (int it = 0; it < 2; ++it) {
        int r = base + it * 8 + oct;
        r = (r < N) ? r : (N - 1);           // grid covers N exactly; safety clamp
        const int* fr = fn + (long)r * 9;
        #pragma unroll
        for (int j = 0; j < 9; ++j) idx[it][j] = __builtin_nontemporal_load(fr + j);
    }

    #pragma unroll
    for (int it = 0; it < 2; ++it) {
        float4v v[9];
        #pragma unroll
        for (int j = 0; j < 9; ++j) {
            const int id = idx[it][j];
            if ((unsigned)id < (unsigned)N) {
                v[j] = *(const float4v*)(x + (long)id * 32 + m8 * 4);
            } else {
                v[j] = (float4v){0.f, 0.f, 0.f, 0.f};
            }
        }
        const float4v g0 = v[0];
        const float4v g1 = v[1] + v[3] + v[5] + v[7];
        const float4v g2 = v[2] + v[4] + v[6] + v[8];
        _Float16* dst = Aw + (it * 8 + oct) * ROWPITCH + m8 * 4;
        *(half4v*)(dst)      = (half4v){(_Float16)g0.x, (_Float16)g0.y, (_Float16)g0.z, (_Float16)g0.w};
        *(half4v*)(dst + 32) = (half4v){(_Float16)g1.x, (_Float16)g1.y, (_Float16)g1.z, (_Float16)g1.w};
        *(half4v*)(dst + 64) = (half4v){(_Float16)g2.x, (_Float16)g2.y, (_Float16)g2.z, (_Float16)g2.w};
    }

    __syncthreads();

    // ---- Phase B: 6 MFMAs per wave (16 rows x 32 outs, K=96) ----
    float4v acc0 = {0.f, 0.f, 0.f, 0.f}, acc1 = {0.f, 0.f, 0.f, 0.f};
    #pragma unroll
    for (int s = 0; s < 3; ++s) {
        half8 a = *(half8*)(Aw + m16 * ROWPITCH + s * 32 + quad * 8);
        acc0 = __builtin_amdgcn_mfma_f32_16x16x32_f16(a, bfrag[s][0], acc0, 0, 0, 0);
        acc1 = __builtin_amdgcn_mfma_f32_16x16x32_f16(a, bfrag[s][1], acc1, 0, 0, 0);
    }

    // Epilogue: C/D layout col = lane&15, row = quad*4 + i. Non-temporal stores
    // keep `out` from evicting x in L3.
    #pragma unroll
    for (int i = 0; i < 4; ++i) {
        const int r = base + quad * 4 + i;
        if (r < N) {
            __builtin_nontemporal_store(acc0[i] + bias0, &out[(long)r * 32 + m16]);
            __builtin_nontemporal_store(acc1[i] + bias1, &out[(long)r * 32 + 16 + m16]);
        }
    }
}

extern "C" void kernel_launch(void* const* d_in, const int* in_sizes, int n_in,
                              void* d_out, int out_size, void* d_ws, size_t ws_size,
                              hipStream_t stream) {
    const float* x    = (const float*)d_in[0];
    const float* w0   = (const float*)d_in[1];
    const float* w1   = (const float*)d_in[2];
    const float* w2   = (const float*)d_in[3];
    const float* bias = (const float*)d_in[4];
    const int*   fn   = (const int*)d_in[5];
    float* out = (float*)d_out;

    const int N = in_sizes[0] / 32;
    const int blocks = (N + ROWS_PER_BLOCK - 1) / ROWS_PER_BLOCK;

    prep_weights<<<1, 384, 0, stream>>>(w0, w1, w2);
    face_conv_kernel<<<blocks, BLOCK, 0, stream>>>(x, bias, fn, out, N);
}